// Round 6
// baseline (309.537 us; speedup 1.0000x reference)
//
#include <hip/hip_runtime.h>
#include <math.h>

#define BB 4
#define HH 56
#define WW 56
#define CC 256
#define NN 3136            // HH*WW
#define SS 3137            // 1 + NN
#define NH 8
#define HD 32
#define M_ROWS (BB * SS)   // 12548
#define SPAD 3200          // padded S for vt rows (63 pad keys)
#define QSCALE (0.17677669529663687f * 1.4426950408889634f)  // 1/sqrt(32) * log2(e)
#define KT 128             // attention key-tile

typedef short short8 __attribute__((ext_vector_type(8)));   // 8 bf16 (4 VGPRs)
typedef short bf4    __attribute__((ext_vector_type(4)));   // 4 bf16 (2 VGPRs)
typedef float f32x4  __attribute__((ext_vector_type(4)));   // MFMA C/D

static __device__ __forceinline__ unsigned short f2bf(float f) {
    union { float f; unsigned u; } a; a.f = f;
    unsigned r = a.u + 0x7FFF + ((a.u >> 16) & 1);   // RNE
    return (unsigned short)(r >> 16);
}
static __device__ __forceinline__ float bf2f(unsigned short h) {
    union { unsigned u; float f; } a; a.u = ((unsigned)h) << 16; return a.f;
}

// ---------------------------------------------------------------------------
// Kernel 0: pre — fused elementwise prep:
//   [0, M_ROWS)        xb = bf16(x_cat)
//   [+768)             wb = bf16(qkv_w)
//   [+M_ROWS)          lepe = bf16(dwconv5x5(x) + bias)   (s=0 row -> 0)
//   [+256)             pwhi/pwlo = bf16 split of proj_w
//   [+256)             vt pad cols [3136,3200) = 0
// ---------------------------------------------------------------------------
__global__ __launch_bounds__(256)
void pre(const float* __restrict__ x, const float* __restrict__ cls,
         const float* __restrict__ qkv_w, const float* __restrict__ proj_w,
         const float* __restrict__ lepe_w, const float* __restrict__ lepe_b,
         unsigned short* __restrict__ xb, unsigned short* __restrict__ wb,
         unsigned short* __restrict__ lepe,
         unsigned short* __restrict__ pwhi, unsigned short* __restrict__ pwlo,
         unsigned short* __restrict__ vt)
{
    const int B0 = M_ROWS;
    const int B1 = B0 + 3 * CC;
    const int B2 = B1 + M_ROWS;
    const int B3 = B2 + CC;
    int blk = blockIdx.x, c = threadIdx.x;
    if (blk < B0) {
        int b = blk / SS, s = blk % SS;
        const float* src = (s == 0) ? (cls + (size_t)b * CC)
                                    : (x + ((size_t)b * NN + (s - 1)) * CC);
        xb[(size_t)blk * CC + c] = f2bf(src[c]);
    } else if (blk < B1) {
        int r = blk - B0;   // 0..767
        wb[(size_t)r * CC + c] = f2bf(qkv_w[(size_t)r * CC + c]);
    } else if (blk < B2) {
        int row = blk - B1;
        int b = row / SS, s = row % SS;
        unsigned short outv = 0;
        if (s > 0) {
            int sp = s - 1;
            int xx = sp % WW, y = sp / WW;
            float acc = lepe_b[c];
            const float* wc = lepe_w + c * 25;
            #pragma unroll
            for (int ky = 0; ky < 5; ++ky) {
                int yy = y + ky - 2;
                if (yy < 0 || yy >= HH) continue;
                #pragma unroll
                for (int kx = 0; kx < 5; ++kx) {
                    int xp = xx + kx - 2;
                    if (xp < 0 || xp >= WW) continue;
                    acc += x[(((size_t)b * HH + yy) * WW + xp) * CC + c] * wc[ky * 5 + kx];
                }
            }
            outv = f2bf(acc);
        }
        lepe[(size_t)row * CC + c] = outv;
    } else if (blk < B3) {
        int r = blk - B2;   // 0..255
        float v = proj_w[(size_t)r * CC + c];
        unsigned short h = f2bf(v);
        pwhi[(size_t)r * CC + c] = h;
        pwlo[(size_t)r * CC + c] = f2bf(v - bf2f(h));
    } else {
        int idx = blk - B3;                 // 0..255, 4 rows each
        int row = idx * 4 + (c >> 6);
        int col = 3136 + (c & 63);
        vt[(size_t)row * SPAD + col] = 0;
    }
}

// ---------------------------------------------------------------------------
// Kernel 1: qkv bf16 MFMA GEMM: [12548x256] @ [768x256]^T
// Grid (100,6): batch-aligned M tiles. Epilogue: qb (QSCALE folded), kb,
// vt[(b*8+h)*32+d][s] (V^T, packed short4 stores).
// ---------------------------------------------------------------------------
__global__ __launch_bounds__(256)
void qkv_mfma(const unsigned short* __restrict__ xb,
              const unsigned short* __restrict__ wb,
              unsigned short* __restrict__ qb, unsigned short* __restrict__ kb,
              unsigned short* __restrict__ vt)
{
    __shared__ unsigned short As[128][76];   // 38 dw stride: frag reads 2-way max
    __shared__ unsigned short Bs[128][76];
    const int tid = threadIdx.x;
    const int w = tid >> 6, lane = tid & 63, lo = lane & 15, hi = lane >> 4;
    const int b0 = blockIdx.x / 25;
    const int s0blk = (blockIdx.x % 25) * 128;
    const int col0 = blockIdx.y * 128;
    const int wm = (w & 1) * 64, wn = (w >> 1) * 64;

    f32x4 acc[4][4] = {};

    for (int k0 = 0; k0 < CC; k0 += 64) {
        __syncthreads();
        #pragma unroll
        for (int i = 0; i < 4; ++i) {
            int chunk = tid + i * 256;          // 0..1023
            int row = chunk >> 3, c8 = (chunk & 7) * 8;
            short8 av = {};
            if (s0blk + row < SS)
                av = *(const short8*)(xb + (size_t)(b0 * SS + s0blk + row) * CC + k0 + c8);
            *(short8*)&As[row][c8] = av;
            short8 bv = *(const short8*)(wb + (size_t)(col0 + row) * CC + k0 + c8);
            *(short8*)&Bs[row][c8] = bv;
        }
        __syncthreads();
        #pragma unroll
        for (int kk = 0; kk < 64; kk += 32) {
            short8 af[4], bf_[4];
            #pragma unroll
            for (int m = 0; m < 4; ++m)
                af[m] = *(const short8*)&As[wm + m * 16 + lo][kk + hi * 8];
            #pragma unroll
            for (int n = 0; n < 4; ++n)
                bf_[n] = *(const short8*)&Bs[wn + n * 16 + lo][kk + hi * 8];
            #pragma unroll
            for (int m = 0; m < 4; ++m)
                #pragma unroll
                for (int n = 0; n < 4; ++n)
                    acc[m][n] = __builtin_amdgcn_mfma_f32_16x16x32_bf16(
                                    af[m], bf_[n], acc[m][n], 0, 0, 0);
        }
    }

    const int part = col0 >> 8;   // 0=q, 1=k, 2=v (block-uniform)
    if (part < 2) {
        #pragma unroll
        for (int m = 0; m < 4; ++m) {
            #pragma unroll
            for (int rr = 0; rr < 4; ++rr) {
                int s = s0blk + wm + m * 16 + hi * 4 + rr;
                if (s >= SS) continue;
                size_t r = (size_t)(b0 * SS + s);
                #pragma unroll
                for (int n = 0; n < 4; ++n) {
                    int cc = (col0 + wn + n * 16 + lo) & 255;
                    float val = acc[m][n][rr];
                    if (part == 0) qb[r * CC + cc] = f2bf(val * QSCALE);
                    else           kb[r * CC + cc] = f2bf(val);
                }
            }
        }
    } else {
        #pragma unroll
        for (int m = 0; m < 4; ++m) {
            int s0 = s0blk + wm + m * 16 + hi * 4;   // multiple of 4
            if (s0 >= SS) continue;
            bool fast = (s0 + 3 < SS);
            #pragma unroll
            for (int n = 0; n < 4; ++n) {
                int cc = (col0 + wn + n * 16 + lo) & 255;
                int hh = cc >> 5, d = cc & 31;
                unsigned short* vrow = vt + (size_t)((b0 * NH + hh) * HD + d) * SPAD;
                if (fast) {
                    bf4 pk;
                    pk[0] = (short)f2bf(acc[m][n][0]);
                    pk[1] = (short)f2bf(acc[m][n][1]);
                    pk[2] = (short)f2bf(acc[m][n][2]);
                    pk[3] = (short)f2bf(acc[m][n][3]);
                    *(bf4*)(vrow + s0) = pk;
                } else {
                    for (int rr = 0; rr < 4 && s0 + rr < SS; ++rr)
                        vrow[s0 + rr] = f2bf(acc[m][n][rr]);
                }
            }
        }
    }
}

// ---------------------------------------------------------------------------
// Kernel 2: bf16 MFMA flash attention, transposed-S, ones-MFMA denominator.
//   S^T = K @ Q^T (16x16x32); P^T = trunc_bf16(exp2(S^T)) in-register;
//   O^T += V^T @ P^T (16x16x16); l = ones_A @ P^T (exact ratio cancellation).
// 128 threads = 2 waves x 32 q; block = 64 q; grid 1600, XCD-swizzled so all
// 50 q-blocks of one (b,h) share bid%8 (K/V slice lives in one XCD L2).
// Epilogue: ohi = bf16(O/(l-63) + lepe)  (63 pad keys contribute exactly 1).
// ---------------------------------------------------------------------------
__global__ __launch_bounds__(128)
void attn_mfma(const unsigned short* __restrict__ qb,
               const unsigned short* __restrict__ kb,
               const unsigned short* __restrict__ vt,
               const unsigned short* __restrict__ lepe,
               unsigned short* __restrict__ ohi)
{
    __shared__ unsigned short Ks[KT][44];     // 22 dw stride: 2-way max
    __shared__ unsigned short Vts[32][140];   // 70 dw stride: 2-way max

    const int tid  = threadIdx.x;
    const int w    = tid >> 6;
    const int lane = tid & 63;
    const int lo   = lane & 15;
    const int hi   = lane >> 4;

    const int bid = blockIdx.x;
    const int r8  = bid & 7;         // XCD residue -> head
    const int j   = bid >> 3;        // 0..199
    const int qc  = j % 50;
    const int b   = j / 50;
    const int h   = r8;
    const int q0w = qc * 64 + w * 32;

    short8 qa[2];
    #pragma unroll
    for (int qg = 0; qg < 2; ++qg) {
        int row = min(q0w + qg * 16 + lo, SS - 1);
        qa[qg] = *(const short8*)(qb + ((size_t)(b * SS + row)) * CC + h * HD + hi * 8);
    }

    f32x4 oacc[2][2] = {};
    f32x4 dacc[2] = {};
    bf4 ones;
    ones[0] = (short)0x3F80; ones[1] = (short)0x3F80;
    ones[2] = (short)0x3F80; ones[3] = (short)0x3F80;

    const int krow = tid >> 2, kd0 = (tid & 3) * 8;    // K: 4 rows/thread
    const int vrow = tid >> 4, vk0 = (tid & 15) * 8;   // V: 4 rows/thread
    const unsigned short* kp0 = kb + ((size_t)b * SS + krow) * CC + h * HD + kd0;
    const unsigned short* vp0 = vt + ((size_t)((b * NH + h) * HD + vrow)) * SPAD + vk0;

    for (int k0 = 0; k0 < SPAD; k0 += KT) {
        __syncthreads();
        #pragma unroll
        for (int i = 0; i < 4; ++i) {
            int gk = k0 + krow + 32 * i;
            short8 kv = {};
            if (gk < SS) kv = *(const short8*)(kp0 + ((size_t)k0 + 32 * i) * CC);
            *(short8*)&Ks[krow + 32 * i][kd0] = kv;
        }
        #pragma unroll
        for (int i = 0; i < 4; ++i) {
            short8 vv = *(const short8*)(vp0 + (size_t)(8 * i) * SPAD + k0);
            *(short8*)&Vts[vrow + 8 * i][vk0] = vv;
        }
        __syncthreads();

        #pragma unroll
        for (int g = 0; g < 8; ++g) {
            short8 kf = *(const short8*)&Ks[g * 16 + lo][hi * 8];
            bf4 vf0 = *(const bf4*)&Vts[lo][g * 16 + hi * 4];
            bf4 vf1 = *(const bf4*)&Vts[16 + lo][g * 16 + hi * 4];
            #pragma unroll
            for (int qg = 0; qg < 2; ++qg) {
                f32x4 st = __builtin_amdgcn_mfma_f32_16x16x32_bf16(
                               kf, qa[qg], (f32x4){0.f, 0.f, 0.f, 0.f}, 0, 0, 0);
                float p0 = __builtin_amdgcn_exp2f(st[0]);
                float p1 = __builtin_amdgcn_exp2f(st[1]);
                float p2 = __builtin_amdgcn_exp2f(st[2]);
                float p3 = __builtin_amdgcn_exp2f(st[3]);
                // truncate to bf16 (bias cancels: denominator uses same P)
                unsigned u01 = __builtin_amdgcn_perm(
                    __float_as_uint(p1), __float_as_uint(p0), 0x07060302u);
                unsigned u23 = __builtin_amdgcn_perm(
                    __float_as_uint(p3), __float_as_uint(p2), 0x07060302u);
                union { unsigned u[2]; bf4 s; } pf;
                pf.u[0] = u01; pf.u[1] = u23;
                oacc[qg][0] = __builtin_amdgcn_mfma_f32_16x16x16bf16_1k(
                                  vf0, pf.s, oacc[qg][0], 0, 0, 0);
                oacc[qg][1] = __builtin_amdgcn_mfma_f32_16x16x16bf16_1k(
                                  vf1, pf.s, oacc[qg][1], 0, 0, 0);
                dacc[qg]    = __builtin_amdgcn_mfma_f32_16x16x16bf16_1k(
                                  ones, pf.s, dacc[qg], 0, 0, 0);
            }
        }
    }

    #pragma unroll
    for (int qg = 0; qg < 2; ++qg) {
        float inv = 1.f / (dacc[qg][0] - 63.f);   // remove 63 pad keys (p=1)
        int rowq = q0w + qg * 16 + lo;
        if (rowq < SS) {
            size_t base = ((size_t)(b * SS + rowq)) * CC + h * HD;
            #pragma unroll
            for (int dt = 0; dt < 2; ++dt) {
                bf4 lep = *(const bf4*)(lepe + base + dt * 16 + hi * 4);
                bf4 pk;
                #pragma unroll
                for (int r = 0; r < 4; ++r) {
                    float val = oacc[qg][dt][r] * inv + bf2f((unsigned short)lep[r]);
                    pk[r] = (short)f2bf(val);
                }
                *(bf4*)(ohi + base + dt * 16 + hi * 4) = pk;
            }
        }
    }
}

// ---------------------------------------------------------------------------
// Kernel 3: proj MFMA GEMM: out = ohi @ (Whi+Wlo)^T + b   (2-term split,
// W pre-split in `pre`). Scatter to (x_out | cls_out).
// ---------------------------------------------------------------------------
__global__ __launch_bounds__(256)
void proj_mfma(const unsigned short* __restrict__ ohi,
               const unsigned short* __restrict__ pwhi,
               const unsigned short* __restrict__ pwlo,
               const float* __restrict__ bias, float* __restrict__ out)
{
    __shared__ unsigned short Ah[64][76];
    __shared__ unsigned short Wh[64][76];
    __shared__ unsigned short Wl[64][76];
    const int tid = threadIdx.x;
    const int w = tid >> 6, lane = tid & 63, lo = lane & 15, hi = lane >> 4;
    const int row0 = blockIdx.x * 64, col0 = blockIdx.y * 64;
    const int wm = (w & 1) * 32, wn = (w >> 1) * 32;

    f32x4 acc[2][2] = {};

    for (int k0 = 0; k0 < CC; k0 += 64) {
        __syncthreads();
        #pragma unroll
        for (int i = 0; i < 2; ++i) {
            int chunk = tid + i * 256;          // 0..511
            int row = chunk >> 3, c8 = (chunk & 7) * 8;
            int gr = row0 + row;
            short8 ah = {};
            if (gr < M_ROWS)
                ah = *(const short8*)(ohi + (size_t)gr * CC + k0 + c8);
            *(short8*)&Ah[row][c8] = ah;
            int wr = col0 + row;
            *(short8*)&Wh[row][c8] = *(const short8*)(pwhi + (size_t)wr * CC + k0 + c8);
            *(short8*)&Wl[row][c8] = *(const short8*)(pwlo + (size_t)wr * CC + k0 + c8);
        }
        __syncthreads();
        #pragma unroll
        for (int kk = 0; kk < 64; kk += 32) {
            short8 ah[2], wh[2], wl[2];
            #pragma unroll
            for (int m = 0; m < 2; ++m)
                ah[m] = *(const short8*)&Ah[wm + m * 16 + lo][kk + hi * 8];
            #pragma unroll
            for (int n = 0; n < 2; ++n) {
                wh[n] = *(const short8*)&Wh[wn + n * 16 + lo][kk + hi * 8];
                wl[n] = *(const short8*)&Wl[wn + n * 16 + lo][kk + hi * 8];
            }
            #pragma unroll
            for (int m = 0; m < 2; ++m)
                #pragma unroll
                for (int n = 0; n < 2; ++n) {
                    acc[m][n] = __builtin_amdgcn_mfma_f32_16x16x32_bf16(
                                    ah[m], wh[n], acc[m][n], 0, 0, 0);
                    acc[m][n] = __builtin_amdgcn_mfma_f32_16x16x32_bf16(
                                    ah[m], wl[n], acc[m][n], 0, 0, 0);
                }
        }
    }

    #pragma unroll
    for (int m = 0; m < 2; ++m) {
        #pragma unroll
        for (int rr = 0; rr < 4; ++rr) {
            int r = row0 + wm + m * 16 + hi * 4 + rr;
            if (r >= M_ROWS) continue;
            int b = r / SS, s = r % SS;
            #pragma unroll
            for (int n = 0; n < 2; ++n) {
                int col = col0 + wn + n * 16 + lo;
                float val = acc[m][n][rr] + bias[col];
                if (s == 0)
                    out[(size_t)BB * NN * CC + (size_t)b * CC + col] = val;
                else
                    out[((size_t)b * NN + (s - 1)) * CC + col] = val;
            }
        }
    }
}

extern "C" void kernel_launch(void* const* d_in, const int* in_sizes, int n_in,
                              void* d_out, int out_size, void* d_ws, size_t ws_size,
                              hipStream_t stream)
{
    const float* x      = (const float*)d_in[0];
    const float* cls    = (const float*)d_in[1];
    const float* qkv_w  = (const float*)d_in[2];
    const float* proj_w = (const float*)d_in[3];
    const float* proj_b = (const float*)d_in[4];
    const float* lepe_w = (const float*)d_in[5];
    const float* lepe_b = (const float*)d_in[6];
    float* out = (float*)d_out;

    // Workspace: no overlays (ws is ~256 MiB; we use ~39.3 MB)
    char* ws = (char*)d_ws;
    unsigned short* qb   = (unsigned short*)(ws + 0);          // 6,424,576
    unsigned short* kb   = (unsigned short*)(ws + 6424576);    // 6,424,576
    unsigned short* vt   = (unsigned short*)(ws + 12849152);   // 6,553,600
    unsigned short* xb   = (unsigned short*)(ws + 19402752);   // 6,424,576
    unsigned short* wb   = (unsigned short*)(ws + 25827328);   //   393,216
    unsigned short* lepe = (unsigned short*)(ws + 26220544);   // 6,424,576
    unsigned short* ohi  = (unsigned short*)(ws + 32645120);   // 6,424,576
    unsigned short* pwhi = (unsigned short*)(ws + 39069696);   //   131,072
    unsigned short* pwlo = (unsigned short*)(ws + 39200768);   //   131,072

    pre      <<<2 * M_ROWS + 3 * CC + 2 * CC, 256, 0, stream>>>(
                 x, cls, qkv_w, proj_w, lepe_w, lepe_b,
                 xb, wb, lepe, pwhi, pwlo, vt);
    qkv_mfma <<<dim3(100, 6), 256, 0, stream>>>(xb, wb, qb, kb, vt);
    attn_mfma<<<1600, 128, 0, stream>>>(qb, kb, vt, lepe, ohi);
    proj_mfma<<<dim3(197, 4), 256, 0, stream>>>(ohi, pwhi, pwlo, proj_b, out);
}

// Round 7
// 278.219 us; speedup vs baseline: 1.1126x; 1.1126x over previous
//
#include <hip/hip_runtime.h>
#include <math.h>

#define BB 4
#define HH 56
#define WW 56
#define CC 256
#define NN 3136            // HH*WW
#define SS 3137            // 1 + NN
#define NH 8
#define HD 32
#define M_ROWS (BB * SS)   // 12548
#define SPAD 3200          // padded S for vt rows (63 pad keys)
#define QSCALE (0.17677669529663687f * 1.4426950408889634f)  // 1/sqrt(32) * log2(e)
#define KT 128             // attention key-tile

typedef short short8 __attribute__((ext_vector_type(8)));   // 8 bf16 (4 VGPRs)
typedef short bf4    __attribute__((ext_vector_type(4)));   // 4 bf16 (2 VGPRs)
typedef float f32x4  __attribute__((ext_vector_type(4)));   // MFMA C/D

static __device__ __forceinline__ unsigned short f2bf(float f) {
    union { float f; unsigned u; } a; a.f = f;
    unsigned r = a.u + 0x7FFF + ((a.u >> 16) & 1);   // RNE
    return (unsigned short)(r >> 16);
}
static __device__ __forceinline__ float bf2f(unsigned short h) {
    union { unsigned u; float f; } a; a.u = ((unsigned)h) << 16; return a.f;
}

// ---------------------------------------------------------------------------
// Kernel 0: pre — xb = bf16(x_cat), wb = bf16(qkv_w), pwhi/pwlo = split of
// proj_w, vt pad cols [3136,3200) = 0.  (lepe moved to its own kernel: it
// reads xb, which this kernel produces.)
// ---------------------------------------------------------------------------
__global__ __launch_bounds__(256)
void pre(const float* __restrict__ x, const float* __restrict__ cls,
         const float* __restrict__ qkv_w, const float* __restrict__ proj_w,
         unsigned short* __restrict__ xb, unsigned short* __restrict__ wb,
         unsigned short* __restrict__ pwhi, unsigned short* __restrict__ pwlo,
         unsigned short* __restrict__ vt)
{
    const int B0 = M_ROWS;
    const int B1 = B0 + 3 * CC;
    const int B2 = B1 + CC;
    int blk = blockIdx.x, c = threadIdx.x;
    if (blk < B0) {
        int b = blk / SS, s = blk % SS;
        const float* src = (s == 0) ? (cls + (size_t)b * CC)
                                    : (x + ((size_t)b * NN + (s - 1)) * CC);
        xb[(size_t)blk * CC + c] = f2bf(src[c]);
    } else if (blk < B1) {
        int r = blk - B0;   // 0..767
        wb[(size_t)r * CC + c] = f2bf(qkv_w[(size_t)r * CC + c]);
    } else if (blk < B2) {
        int r = blk - B1;   // 0..255
        float v = proj_w[(size_t)r * CC + c];
        unsigned short h = f2bf(v);
        pwhi[(size_t)r * CC + c] = h;
        pwlo[(size_t)r * CC + c] = f2bf(v - bf2f(h));
    } else {
        int idx = blk - B2;                 // 0..255, 4 rows each
        int row = idx * 4 + (c >> 6);
        int col = 3136 + (c & 63);
        vt[(size_t)row * SPAD + col] = 0;
    }
}

// ---------------------------------------------------------------------------
// Kernel 1: LePE depthwise 5x5 conv + bias -> bf16 [M_ROWS][256].
// Reads bf16 xb (rows s>=1 are exactly bf16(x)) — halves conv traffic vs
// fp32 x. Block = one (b,s) row; bounds are block-uniform (no divergence).
// ---------------------------------------------------------------------------
__global__ __launch_bounds__(256)
void lepe_kernel(const unsigned short* __restrict__ xb,
                 const float* __restrict__ w, const float* __restrict__ bias,
                 unsigned short* __restrict__ lepe)
{
    int blk = blockIdx.x, c = threadIdx.x;
    int b = blk / SS, s = blk % SS;
    unsigned short outv = 0;
    if (s > 0) {
        int sp = s - 1;
        int xx = sp % WW, y = sp / WW;
        float acc = bias[c];
        const float* wc = w + c * 25;
        const unsigned short* xrow = xb + ((size_t)b * SS + 1) * CC + c;
        #pragma unroll
        for (int ky = 0; ky < 5; ++ky) {
            int yy = y + ky - 2;
            if (yy < 0 || yy >= HH) continue;
            #pragma unroll
            for (int kx = 0; kx < 5; ++kx) {
                int xp = xx + kx - 2;
                if (xp < 0 || xp >= WW) continue;
                acc += bf2f(xrow[(size_t)(yy * WW + xp) * CC]) * wc[ky * 5 + kx];
            }
        }
        outv = f2bf(acc);
    }
    lepe[(size_t)blk * CC + c] = outv;
}

// ---------------------------------------------------------------------------
// Kernel 2: qkv bf16 MFMA GEMM: [12548x256] @ [768x256]^T
// 64x128 tiles, grid (200,6): bx = b0*50 + s-tile (batch-aligned M so the
// V^T epilogue's 4-row packs stay 4-aligned in s). Epilogue: qb (QSCALE
// folded), kb, vt[(b*8+h)*32+d][s] (V^T, packed short4 stores).
// ---------------------------------------------------------------------------
__global__ __launch_bounds__(256)
void qkv_mfma(const unsigned short* __restrict__ xb,
              const unsigned short* __restrict__ wb,
              unsigned short* __restrict__ qb, unsigned short* __restrict__ kb,
              unsigned short* __restrict__ vt)
{
    __shared__ unsigned short As[64][76];    // 38 dw stride: frag reads 2-way max
    __shared__ unsigned short Bs[128][76];
    const int tid = threadIdx.x;
    const int w = tid >> 6, lane = tid & 63, lo = lane & 15, hi = lane >> 4;
    const int b0 = blockIdx.x / 50;
    const int s0blk = (blockIdx.x % 50) * 64;
    const int col0 = blockIdx.y * 128;
    const int wm = (w & 1) * 32, wn = (w >> 1) * 64;

    f32x4 acc[2][4] = {};

    for (int k0 = 0; k0 < CC; k0 += 64) {
        __syncthreads();
        #pragma unroll
        for (int i = 0; i < 2; ++i) {
            int chunk = tid + i * 256;          // 0..511 (A: 64 rows x 8 chunks)
            int row = chunk >> 3, c8 = (chunk & 7) * 8;
            short8 av = {};
            if (s0blk + row < SS)
                av = *(const short8*)(xb + (size_t)(b0 * SS + s0blk + row) * CC + k0 + c8);
            *(short8*)&As[row][c8] = av;
        }
        #pragma unroll
        for (int i = 0; i < 4; ++i) {
            int chunk = tid + i * 256;          // 0..1023 (B: 128 rows x 8 chunks)
            int row = chunk >> 3, c8 = (chunk & 7) * 8;
            short8 bv = *(const short8*)(wb + (size_t)(col0 + row) * CC + k0 + c8);
            *(short8*)&Bs[row][c8] = bv;
        }
        __syncthreads();
        #pragma unroll
        for (int kk = 0; kk < 64; kk += 32) {
            short8 af[2], bf_[4];
            #pragma unroll
            for (int m = 0; m < 2; ++m)
                af[m] = *(const short8*)&As[wm + m * 16 + lo][kk + hi * 8];
            #pragma unroll
            for (int n = 0; n < 4; ++n)
                bf_[n] = *(const short8*)&Bs[wn + n * 16 + lo][kk + hi * 8];
            #pragma unroll
            for (int m = 0; m < 2; ++m)
                #pragma unroll
                for (int n = 0; n < 4; ++n)
                    acc[m][n] = __builtin_amdgcn_mfma_f32_16x16x32_bf16(
                                    af[m], bf_[n], acc[m][n], 0, 0, 0);
        }
    }

    const int part = col0 >> 8;   // 0=q, 1=k, 2=v (block-uniform)
    if (part < 2) {
        #pragma unroll
        for (int m = 0; m < 2; ++m) {
            #pragma unroll
            for (int rr = 0; rr < 4; ++rr) {
                int s = s0blk + wm + m * 16 + hi * 4 + rr;
                if (s >= SS) continue;
                size_t r = (size_t)(b0 * SS + s);
                #pragma unroll
                for (int n = 0; n < 4; ++n) {
                    int cc = (col0 + wn + n * 16 + lo) & 255;
                    float val = acc[m][n][rr];
                    if (part == 0) qb[r * CC + cc] = f2bf(val * QSCALE);
                    else           kb[r * CC + cc] = f2bf(val);
                }
            }
        }
    } else {
        #pragma unroll
        for (int m = 0; m < 2; ++m) {
            int s0 = s0blk + wm + m * 16 + hi * 4;   // multiple of 4
            if (s0 >= SS) continue;
            bool fast = (s0 + 3 < SS);
            #pragma unroll
            for (int n = 0; n < 4; ++n) {
                int cc = (col0 + wn + n * 16 + lo) & 255;
                int hh = cc >> 5, d = cc & 31;
                unsigned short* vrow = vt + (size_t)((b0 * NH + hh) * HD + d) * SPAD;
                if (fast) {
                    bf4 pk;
                    pk[0] = (short)f2bf(acc[m][n][0]);
                    pk[1] = (short)f2bf(acc[m][n][1]);
                    pk[2] = (short)f2bf(acc[m][n][2]);
                    pk[3] = (short)f2bf(acc[m][n][3]);
                    *(bf4*)(vrow + s0) = pk;
                } else {
                    for (int rr = 0; rr < 4 && s0 + rr < SS; ++rr)
                        vrow[s0 + rr] = f2bf(acc[m][n][rr]);
                }
            }
        }
    }
}

// ---------------------------------------------------------------------------
// Kernel 3: bf16 MFMA flash attention, transposed-S, ones-MFMA denominator.
//   S^T = K @ Q^T (16x16x32); P^T = trunc_bf16(exp2(S^T)) in-register;
//   O^T += V^T @ P^T (16x16x16); l = ones_A @ P^T (exact ratio cancellation).
// 256 threads = 4 waves x 16 q; block = 64 q; grid 1600, XCD-swizzled
// (bid&7 = head -> each XCD keeps one head's K/V slice in its L2).
// LDS 20224 B -> 7 blocks/CU; grid 6.25 blocks/CU -> ~25 waves/CU.
// Epilogue: ohi = bf16(O/(l-63) + lepe)  (63 pad keys contribute exactly 1).
// ---------------------------------------------------------------------------
__global__ __launch_bounds__(256)
void attn_mfma(const unsigned short* __restrict__ qb,
               const unsigned short* __restrict__ kb,
               const unsigned short* __restrict__ vt,
               const unsigned short* __restrict__ lepe,
               unsigned short* __restrict__ ohi)
{
    __shared__ unsigned short Ks[KT][44];     // 22 dw stride: 2-way max
    __shared__ unsigned short Vts[32][140];   // 70 dw stride: 2-way max

    const int tid  = threadIdx.x;
    const int w    = tid >> 6;
    const int lane = tid & 63;
    const int lo   = lane & 15;
    const int hi   = lane >> 4;

    const int bid = blockIdx.x;
    const int h   = bid & 7;         // XCD residue -> head
    const int j   = bid >> 3;        // 0..199
    const int qc  = j % 50;
    const int b   = j / 50;
    const int q0w = qc * 64 + w * 16;

    const int qrow = min(q0w + lo, SS - 1);
    const short8 qa = *(const short8*)(qb + ((size_t)(b * SS + qrow)) * CC + h * HD + hi * 8);

    f32x4 oacc[2] = {};
    f32x4 dacc = {};
    bf4 ones;
    ones[0] = (short)0x3F80; ones[1] = (short)0x3F80;
    ones[2] = (short)0x3F80; ones[3] = (short)0x3F80;

    const int krow = tid >> 2, kd0 = (tid & 3) * 8;    // K: 2 rows/thread
    const int vrow = tid >> 4, vk0 = (tid & 15) * 8;   // V: 2 rows/thread
    const unsigned short* kp0 = kb + ((size_t)b * SS + krow) * CC + h * HD + kd0;
    const unsigned short* vp0 = vt + ((size_t)((b * NH + h) * HD + vrow)) * SPAD + vk0;

    for (int k0 = 0; k0 < SPAD; k0 += KT) {
        __syncthreads();
        {
            short8 kv0 = {}, kv1 = {};
            if (k0 + krow < SS)      kv0 = *(const short8*)(kp0 + (size_t)k0 * CC);
            if (k0 + 64 + krow < SS) kv1 = *(const short8*)(kp0 + (size_t)(k0 + 64) * CC);
            *(short8*)&Ks[krow][kd0]      = kv0;
            *(short8*)&Ks[64 + krow][kd0] = kv1;
            short8 vv0 = *(const short8*)(vp0 + k0);
            short8 vv1 = *(const short8*)(vp0 + (size_t)16 * SPAD + k0);
            *(short8*)&Vts[vrow][vk0]      = vv0;
            *(short8*)&Vts[16 + vrow][vk0] = vv1;
        }
        __syncthreads();

        #pragma unroll
        for (int g = 0; g < 8; ++g) {
            short8 kf = *(const short8*)&Ks[g * 16 + lo][hi * 8];
            bf4 vf0 = *(const bf4*)&Vts[lo][g * 16 + hi * 4];
            bf4 vf1 = *(const bf4*)&Vts[16 + lo][g * 16 + hi * 4];
            f32x4 st = __builtin_amdgcn_mfma_f32_16x16x32_bf16(
                           kf, qa, (f32x4){0.f, 0.f, 0.f, 0.f}, 0, 0, 0);
            float p0 = __builtin_amdgcn_exp2f(st[0]);
            float p1 = __builtin_amdgcn_exp2f(st[1]);
            float p2 = __builtin_amdgcn_exp2f(st[2]);
            float p3 = __builtin_amdgcn_exp2f(st[3]);
            // truncate to bf16 (bias cancels: denominator uses same P)
            unsigned u01 = __builtin_amdgcn_perm(
                __float_as_uint(p1), __float_as_uint(p0), 0x07060302u);
            unsigned u23 = __builtin_amdgcn_perm(
                __float_as_uint(p3), __float_as_uint(p2), 0x07060302u);
            union { unsigned u[2]; bf4 s; } pf;
            pf.u[0] = u01; pf.u[1] = u23;
            oacc[0] = __builtin_amdgcn_mfma_f32_16x16x16bf16_1k(vf0, pf.s, oacc[0], 0, 0, 0);
            oacc[1] = __builtin_amdgcn_mfma_f32_16x16x16bf16_1k(vf1, pf.s, oacc[1], 0, 0, 0);
            dacc    = __builtin_amdgcn_mfma_f32_16x16x16bf16_1k(ones, pf.s, dacc, 0, 0, 0);
        }
    }

    float inv = 1.f / (dacc[0] - 63.f);   // remove 63 pad keys (p=1 each)
    int rowq = q0w + lo;
    if (rowq < SS) {
        size_t base = ((size_t)(b * SS + rowq)) * CC + h * HD;
        #pragma unroll
        for (int dt = 0; dt < 2; ++dt) {
            bf4 lep = *(const bf4*)(lepe + base + dt * 16 + hi * 4);
            bf4 pk;
            #pragma unroll
            for (int r = 0; r < 4; ++r) {
                float val = oacc[dt][r] * inv + bf2f((unsigned short)lep[r]);
                pk[r] = (short)f2bf(val);
            }
            *(bf4*)(ohi + base + dt * 16 + hi * 4) = pk;
        }
    }
}

// ---------------------------------------------------------------------------
// Kernel 4: proj MFMA GEMM: out = ohi @ (Whi+Wlo)^T + b   (2-term split,
// W pre-split in `pre`). Scatter to (x_out | cls_out).
// ---------------------------------------------------------------------------
__global__ __launch_bounds__(256)
void proj_mfma(const unsigned short* __restrict__ ohi,
               const unsigned short* __restrict__ pwhi,
               const unsigned short* __restrict__ pwlo,
               const float* __restrict__ bias, float* __restrict__ out)
{
    __shared__ unsigned short Ah[64][76];
    __shared__ unsigned short Wh[64][76];
    __shared__ unsigned short Wl[64][76];
    const int tid = threadIdx.x;
    const int w = tid >> 6, lane = tid & 63, lo = lane & 15, hi = lane >> 4;
    const int row0 = blockIdx.x * 64, col0 = blockIdx.y * 64;
    const int wm = (w & 1) * 32, wn = (w >> 1) * 32;

    f32x4 acc[2][2] = {};

    for (int k0 = 0; k0 < CC; k0 += 64) {
        __syncthreads();
        #pragma unroll
        for (int i = 0; i < 2; ++i) {
            int chunk = tid + i * 256;          // 0..511
            int row = chunk >> 3, c8 = (chunk & 7) * 8;
            int gr = row0 + row;
            short8 ah = {};
            if (gr < M_ROWS)
                ah = *(const short8*)(ohi + (size_t)gr * CC + k0 + c8);
            *(short8*)&Ah[row][c8] = ah;
            int wr = col0 + row;
            *(short8*)&Wh[row][c8] = *(const short8*)(pwhi + (size_t)wr * CC + k0 + c8);
            *(short8*)&Wl[row][c8] = *(const short8*)(pwlo + (size_t)wr * CC + k0 + c8);
        }
        __syncthreads();
        #pragma unroll
        for (int kk = 0; kk < 64; kk += 32) {
            short8 ah[2], wh[2], wl[2];
            #pragma unroll
            for (int m = 0; m < 2; ++m)
                ah[m] = *(const short8*)&Ah[wm + m * 16 + lo][kk + hi * 8];
            #pragma unroll
            for (int n = 0; n < 2; ++n) {
                wh[n] = *(const short8*)&Wh[wn + n * 16 + lo][kk + hi * 8];
                wl[n] = *(const short8*)&Wl[wn + n * 16 + lo][kk + hi * 8];
            }
            #pragma unroll
            for (int m = 0; m < 2; ++m)
                #pragma unroll
                for (int n = 0; n < 2; ++n) {
                    acc[m][n] = __builtin_amdgcn_mfma_f32_16x16x32_bf16(
                                    ah[m], wh[n], acc[m][n], 0, 0, 0);
                    acc[m][n] = __builtin_amdgcn_mfma_f32_16x16x32_bf16(
                                    ah[m], wl[n], acc[m][n], 0, 0, 0);
                }
        }
    }

    #pragma unroll
    for (int m = 0; m < 2; ++m) {
        #pragma unroll
        for (int rr = 0; rr < 4; ++rr) {
            int r = row0 + wm + m * 16 + hi * 4 + rr;
            if (r >= M_ROWS) continue;
            int b = r / SS, s = r % SS;
            #pragma unroll
            for (int n = 0; n < 2; ++n) {
                int col = col0 + wn + n * 16 + lo;
                float val = acc[m][n][rr] + bias[col];
                if (s == 0)
                    out[(size_t)BB * NN * CC + (size_t)b * CC + col] = val;
                else
                    out[((size_t)b * NN + (s - 1)) * CC + col] = val;
            }
        }
    }
}

extern "C" void kernel_launch(void* const* d_in, const int* in_sizes, int n_in,
                              void* d_out, int out_size, void* d_ws, size_t ws_size,
                              hipStream_t stream)
{
    const float* x      = (const float*)d_in[0];
    const float* cls    = (const float*)d_in[1];
    const float* qkv_w  = (const float*)d_in[2];
    const float* proj_w = (const float*)d_in[3];
    const float* proj_b = (const float*)d_in[4];
    const float* lepe_w = (const float*)d_in[5];
    const float* lepe_b = (const float*)d_in[6];
    float* out = (float*)d_out;

    // Workspace: no overlays (ws ~256 MiB; we use ~39.3 MB)
    char* ws = (char*)d_ws;
    unsigned short* qb   = (unsigned short*)(ws + 0);          // 6,424,576
    unsigned short* kb   = (unsigned short*)(ws + 6424576);    // 6,424,576
    unsigned short* vt   = (unsigned short*)(ws + 12849152);   // 6,553,600
    unsigned short* xb   = (unsigned short*)(ws + 19402752);   // 6,424,576
    unsigned short* wb   = (unsigned short*)(ws + 25827328);   //   393,216
    unsigned short* lepe = (unsigned short*)(ws + 26220544);   // 6,424,576
    unsigned short* ohi  = (unsigned short*)(ws + 32645120);   // 6,424,576
    unsigned short* pwhi = (unsigned short*)(ws + 39069696);   //   131,072
    unsigned short* pwlo = (unsigned short*)(ws + 39200768);   //   131,072

    pre        <<<M_ROWS + 3 * CC + CC + 256, 256, 0, stream>>>(
                   x, cls, qkv_w, proj_w, xb, wb, pwhi, pwlo, vt);
    lepe_kernel<<<M_ROWS, 256, 0, stream>>>(xb, lepe_w, lepe_b, lepe);
    qkv_mfma   <<<dim3(200, 6), 256, 0, stream>>>(xb, wb, qb, kb, vt);
    attn_mfma  <<<1600, 256, 0, stream>>>(qb, kb, vt, lepe, ohi);
    proj_mfma  <<<dim3(197, 4), 256, 0, stream>>>(ohi, pwhi, pwlo, proj_b, out);
}